// Round 3
// baseline (565.299 us; speedup 1.0000x reference)
//
#include <hip/hip_runtime.h>
#include <math.h>

// RG-LRU: B=4, L=8192, W=1024, H=8, bw=128.
#define NB 4
#define NL 8192
#define NW 1024
#define NH 8
#define BWID 128
#define POWERF 8.0f

#define TM 64             // timesteps per gates block == scan chunk length
#define NRC (NL / TM)     // 128 chunks
#define C2 NRC
#define XP 136            // LDS pitch in bf16 units: rows 16B-aligned, conflicts <=4-way

typedef __attribute__((ext_vector_type(8))) short s8v;     // 8 bf16 (4 VGPR)
typedef __attribute__((ext_vector_type(16))) float f16v;   // 32x32 accumulator
typedef __attribute__((ext_vector_type(4))) unsigned short us4;

__device__ __forceinline__ unsigned short f2bf(float f) {  // RNE fp32->bf16
  unsigned u = __builtin_bit_cast(unsigned, f);
  u += 0x7fff + ((u >> 16) & 1);
  return (unsigned short)(u >> 16);
}
__device__ __forceinline__ float bf2f(unsigned short h) {
  unsigned u = ((unsigned)h) << 16;
  return __builtin_bit_cast(float, u);
}

// ---- prep: W[h][k][n] f32 -> wt[(mat*2+split)][h][n][k] bf16 (transposed) ----
__global__ void prep_w(const float* __restrict__ w_in,
                       const float* __restrict__ w_a,
                       unsigned short* __restrict__ wt) {
  const int idx = blockIdx.x * 256 + threadIdx.x; // 0..1023 -> (h, n)
  const int h = idx >> 7;
  const int n = idx & 127;
  for (int mat = 0; mat < 2; ++mat) {
    const float* w = (mat ? w_a : w_in) + h * BWID * BWID;
    unsigned short* hi = wt + (((size_t)(mat * 2 + 0) * NH + h) * BWID + n) * BWID;
    unsigned short* lo = wt + (((size_t)(mat * 2 + 1) * NH + h) * BWID + n) * BWID;
    for (int k = 0; k < BWID; ++k) {
      const float f = w[k * BWID + n];
      const unsigned short hb = f2bf(f);
      hi[k] = hb;
      lo[k] = f2bf(f - bf2f(hb));
    }
  }
}

// ---- K1: MFMA gates + epilogue + fused per-chunk local scan ----
// Block = (b, h, 64-row chunk). 4 waves: wave = (rt = rows 32*rt.., cg = cols 64*cg..).
// A-frags (hi/lo) preloaded to VGPRs from LDS bf16 tile; B-frags read from
// L2-resident transposed-bf16 W; 3-MFMA split per tile; epilogue in-register.
__global__ __launch_bounds__(256, 2)
void gates_kernel(const float* __restrict__ x, const float* __restrict__ a_param,
                  const unsigned short* __restrict__ wt,
                  const float* __restrict__ b_in, const float* __restrict__ b_a,
                  float* __restrict__ a_out, float* __restrict__ xn_out,
                  float* __restrict__ Aprod, float* __restrict__ hend) {
  __shared__ unsigned short sXh[TM * XP];
  __shared__ unsigned short sXl[TM * XP];

  const int blk = blockIdx.x;
  const int rc = blk % NRC;
  const int h  = (blk / NRC) % NH;
  const int b  = blk / (NRC * NH);
  const int tid = threadIdx.x;
  const int wid = tid >> 6;
  const int rt = wid & 1;
  const int cg = wid >> 1;
  const int lane = tid & 63;
  const int ln = lane & 31;
  const int lh = lane >> 5;

  const size_t xbase = ((size_t)b * NL + (size_t)rc * TM) * NW + h * BWID;

  // stage x tile 64x128 as bf16 hi/lo (coalesced float4 reads)
#pragma unroll
  for (int i = 0; i < 8; ++i) {
    const int idx = tid + 256 * i;
    const int row = idx >> 5;
    const int c4 = (idx & 31) * 4;
    const float4 v = *(const float4*)(x + xbase + (size_t)row * NW + c4);
    const float vf[4] = {v.x, v.y, v.z, v.w};
    us4 hv, lv;
#pragma unroll
    for (int j = 0; j < 4; ++j) {
      const unsigned short hb = f2bf(vf[j]);
      hv[j] = hb;
      lv[j] = f2bf(vf[j] - bf2f(hb));
    }
    *(us4*)(sXh + row * XP + c4) = hv;
    *(us4*)(sXl + row * XP + c4) = lv;
  }
  __syncthreads();

  // preload A fragments: A[m=ln][k = ks*16 + lh*8 + j]
  s8v ahi[8], alo[8];
  const int arow = rt * 32 + ln;
#pragma unroll
  for (int ks = 0; ks < 8; ++ks) {
    ahi[ks] = *(const s8v*)(sXh + arow * XP + ks * 16 + lh * 8);
    alo[ks] = *(const s8v*)(sXl + arow * XP + ks * 16 + lh * 8);
  }

  f16v acc[2][2]; // [mat][ct]
#pragma unroll
  for (int m = 0; m < 2; ++m)
#pragma unroll
    for (int c = 0; c < 2; ++c)
#pragma unroll
      for (int r = 0; r < 16; ++r) acc[m][c][r] = 0.f;

  const unsigned short* wb[4];
#pragma unroll
  for (int q = 0; q < 4; ++q)
    wb[q] = wt + ((size_t)q * NH + h) * BWID * BWID;

#pragma unroll
  for (int ks = 0; ks < 8; ++ks) {
    const int ko = ks * 16 + lh * 8;
#pragma unroll
    for (int ct = 0; ct < 2; ++ct) {
      const int n = cg * 64 + ct * 32 + ln;
#pragma unroll
      for (int mat = 0; mat < 2; ++mat) {
        const s8v bh = *(const s8v*)(wb[mat * 2 + 0] + (size_t)n * BWID + ko);
        const s8v bl = *(const s8v*)(wb[mat * 2 + 1] + (size_t)n * BWID + ko);
        acc[mat][ct] = __builtin_amdgcn_mfma_f32_32x32x16_bf16(ahi[ks], bh, acc[mat][ct], 0, 0, 0);
        acc[mat][ct] = __builtin_amdgcn_mfma_f32_32x32x16_bf16(alo[ks], bh, acc[mat][ct], 0, 0, 0);
        acc[mat][ct] = __builtin_amdgcn_mfma_f32_32x32x16_bf16(ahi[ks], bl, acc[mat][ct], 0, 0, 0);
      }
    }
  }

  // epilogue: C/D col = ln, row = (reg&3) + 8*(reg>>2) + 4*lh  [m74/m101]
#pragma unroll
  for (int ct = 0; ct < 2; ++ct) {
    const int colL = cg * 64 + ct * 32 + ln;
    const int ch = h * BWID + colL;
    const float bx = b_in[ch];
    const float ba = b_a[ch];
    const float sp = log1pf(expf(a_param[ch]));
#pragma unroll
    for (int reg = 0; reg < 16; ++reg) {
      const int row = rt * 32 + (reg & 3) + 8 * (reg >> 2) + 4 * lh;
      const size_t o = xbase + (size_t)row * NW + colL;
      const float xv = x[o];
      const float zx = acc[0][ct][reg] + bx;
      const float za = acc[1][ct][reg] + ba;
      const float gx = 1.f / (1.f + __expf(-zx));
      const float ga = 1.f / (1.f + __expf(-za));
      const float la = -POWERF * ga * sp;
      const float av = __expf(la);
      const float asq = __expf(2.f * la);
      const float xn = xv * gx * sqrtf(fmaxf(1.f - asq, 0.f));
      a_out[o] = av;
      xn_out[o] = xn;
    }
  }

  __threadfence_block();
  __syncthreads();

  // fused local scan over this chunk (L2-hot re-read; kills scan_local kernel)
  if (tid < BWID) {
    float hh = 0.f, A = 1.f;
    const float* ap = a_out + xbase + tid;
    const float* xp = xn_out + xbase + tid;
#pragma unroll 8
    for (int t = 0; t < TM; ++t) {
      const float av = ap[(size_t)t * NW];
      const float xv = xp[(size_t)t * NW];
      hh = fmaf(av, hh, xv);
      A *= av;
    }
    const size_t co = ((size_t)rc * NB + b) * NW + h * BWID + tid;
    Aprod[co] = A;
    hend[co] = hh;
  }
}

// ---- K3: serial prefix over chunk carries -> exclusive h_init per chunk ----
__global__ void scan_carry(const float* __restrict__ Aprod,
                           const float* __restrict__ hend,
                           float* __restrict__ hinit) {
  const int tid = blockIdx.x * blockDim.x + threadIdx.x; // 0..1023
  const int b = tid >> 8;
  const int w4 = tid & 255;
  float c0 = 0.f, c1 = 0.f, c2 = 0.f, c3 = 0.f;
#pragma unroll 8
  for (int c = 0; c < C2; ++c) {
    const size_t o = ((size_t)c * NB + b) * NW + 4 * w4;
    *(float4*)(hinit + o) = make_float4(c0, c1, c2, c3); // exclusive
    const float4 A = *(const float4*)(Aprod + o);
    const float4 he = *(const float4*)(hend + o);
    c0 = fmaf(A.x, c0, he.x);
    c1 = fmaf(A.y, c1, he.y);
    c2 = fmaf(A.z, c2, he.z);
    c3 = fmaf(A.w, c3, he.w);
  }
}

// ---- K4: re-scan each chunk from h_init, in place over x_norm ----
__global__ __launch_bounds__(256)
void scan_final(const float* __restrict__ a_ws,
                const float* __restrict__ hinit,
                float* __restrict__ out) {
  const int blk = blockIdx.x; // b*C2 + c
  const int c = blk % C2;
  const int b = blk / C2;
  const int w4 = threadIdx.x; // 256 threads x float4 = 1024 channels
  const size_t hidx = ((size_t)c * NB + b) * NW + 4 * w4;
  const float4 hi = *(const float4*)(hinit + hidx);
  float h0 = hi.x, h1 = hi.y, h2 = hi.z, h3 = hi.w;
  const size_t base = ((size_t)b * NL + (size_t)c * TM) * NW + 4 * w4;
#pragma unroll 8
  for (int t = 0; t < TM; ++t) {
    const size_t o = base + (size_t)t * NW;
    const float4 a = *(const float4*)(a_ws + o);
    const float4 xv = *(const float4*)(out + o);
    h0 = fmaf(a.x, h0, xv.x);
    h1 = fmaf(a.y, h1, xv.y);
    h2 = fmaf(a.z, h2, xv.z);
    h3 = fmaf(a.w, h3, xv.w);
    *(float4*)(out + o) = make_float4(h0, h1, h2, h3);
  }
}

extern "C" void kernel_launch(void* const* d_in, const int* in_sizes, int n_in,
                              void* d_out, int out_size, void* d_ws, size_t ws_size,
                              hipStream_t stream) {
  const float* x       = (const float*)d_in[0];
  const float* a_param = (const float*)d_in[1];
  const float* w_in    = (const float*)d_in[2];
  const float* b_in    = (const float*)d_in[3];
  const float* w_a     = (const float*)d_in[4];
  const float* b_a     = (const float*)d_in[5];
  float* out = (float*)d_out;

  // ws: a (128 MB) | Aprod, hend, hinit (2 MB each) | wt bf16 (1 MB)
  float* a_ws  = (float*)d_ws;
  float* Aprod = a_ws + (size_t)NB * NL * NW;
  float* hend  = Aprod + (size_t)C2 * NB * NW;
  float* hinit = hend + (size_t)C2 * NB * NW;
  unsigned short* wt = (unsigned short*)(hinit + (size_t)C2 * NB * NW);

  prep_w<<<4, 256, 0, stream>>>(w_in, w_a, wt);
  gates_kernel<<<NB * NH * NRC, 256, 0, stream>>>(
      x, a_param, wt, b_in, b_a, a_ws, out, Aprod, hend);
  scan_carry<<<4, 256, 0, stream>>>(Aprod, hend, hinit);
  scan_final<<<NB * C2, 256, 0, stream>>>(a_ws, hinit, out);
}